// Round 14
// baseline (223.284 us; speedup 1.0000x reference)
//
#include <hip/hip_runtime.h>
#include <hip/hip_fp16.h>

#define NF 128    // feature dim, fixed by the problem
#define KC 64     // edge chunks
#define NPART 4   // node partitions (N/4 ints must fit LDS: 12500*4B = 50KB)
#define NPMAX 12544

typedef _Float16 half8  __attribute__((ext_vector_type(8)));
typedef _Float16 half4v __attribute__((ext_vector_type(4)));
typedef float    floatx4 __attribute__((ext_vector_type(4)));

// ---------------- count2: LDS histogram per (chunk, partition) -------------------
// Block b: partition p=b&3, chunk c=b>>2. Zero global atomics. pcnt is uint8
// (per-chunk counts <=~10, per-bin prefix <= deg <=~60 << 255).
__global__ __launch_bounds__(512) void count2_k(
    const int* __restrict__ dst, unsigned char* __restrict__ pcnt,
    int E, int N, int Ec)
{
    __shared__ int lcnt[NPMAX];
    const int p = blockIdx.x & 3, c = blockIdx.x >> 2;
    const int Np = (N + 3) >> 2;
    const int lo = p * Np, hi = min(lo + Np, N);
    const int sz = hi - lo;
    for (int i = threadIdx.x; i < sz; i += 512) lcnt[i] = 0;
    __syncthreads();

    const int e0 = c * Ec, e1 = min(e0 + Ec, E);
    for (int e = e0 + (int)threadIdx.x * 4; e + 3 < e1; e += 512 * 4) {
        int4 d = *(const int4*)(dst + e);
        if (d.x >= lo && d.x < hi) atomicAdd(&lcnt[d.x - lo], 1);
        if (d.y >= lo && d.y < hi) atomicAdd(&lcnt[d.y - lo], 1);
        if (d.z >= lo && d.z < hi) atomicAdd(&lcnt[d.z - lo], 1);
        if (d.w >= lo && d.w < hi) atomicAdd(&lcnt[d.w - lo], 1);
    }
    int rem0 = e0 + ((e1 - e0) & ~3);
    for (int e = rem0 + (int)threadIdx.x; e < e1; e += 512) {
        int d = dst[e];
        if (d >= lo && d < hi) atomicAdd(&lcnt[d - lo], 1);
    }
    __syncthreads();
    for (int i = threadIdx.x; i < sz; i += 512)
        pcnt[(size_t)c * N + lo + i] = (unsigned char)lcnt[i];
}

// ---------------- pscan2 (+fused W-transpose) ------------------------------------
__global__ __launch_bounds__(256) void pscan2_k(
    unsigned char* __restrict__ pcnt, float* __restrict__ dinv,
    int* __restrict__ rowptr, int* __restrict__ blocksum, int n, int N, int nb,
    const float* __restrict__ W1, const float* __restrict__ W2,
    __half* __restrict__ WT1, __half* __restrict__ WT2)
{
    if ((int)blockIdx.x >= nb) {
        int idx = ((int)blockIdx.x - nb) * 256 + threadIdx.x;   // 0..32767
        const float* W = (idx < 16384) ? W1 : W2;
        __half* WT     = (idx < 16384) ? WT1 : WT2;
        int j = idx & 16383;
        int nn = j & 127, k = j >> 7;
        WT[nn * NF + k] = __float2half(W[k * NF + nn]);
        return;
    }
    __shared__ int sm[256];
    int tid = threadIdx.x;
    int bin = blockIdx.x * 256 + tid;
    int total = 0;
    if (bin < n) {
        #pragma unroll 4
        for (int c = 0; c < KC; c++) {
            size_t o = (size_t)c * N + bin;
            int v = pcnt[o];
            pcnt[o] = (unsigned char)total;   // exclusive chunk prefix (coff)
            total += v;
        }
        dinv[bin] = rsqrtf((float)total + 1.0f);  // +1 = self-loop
    }
    sm[tid] = total;
    __syncthreads();
    #pragma unroll
    for (int d = 1; d < 256; d <<= 1) {
        int t = (tid >= d) ? sm[tid - d] : 0;
        __syncthreads();
        sm[tid] += t;
        __syncthreads();
    }
    if (bin < n) rowptr[bin] = sm[tid] - total;    // local exclusive prefix
    if (tid == 255) blocksum[blockIdx.x] = sm[255];
}

// ---------------- MFMA GEMM body (512 threads, 128 rows/block) -------------------
template<bool F32IN>
__device__ __forceinline__ void gemm_body512(
    const void* __restrict__ Xv, const __half* __restrict__ WT,
    const float* __restrict__ dinv, __half* __restrict__ out, int M, int bid,
    __half (*wlds)[136])
{
    const int tid = threadIdx.x;
    {   // stage WT (128x128 halves): 4 threads/row, 32 halves each
        int r = tid >> 2;
        int c0 = (tid & 3) * 32;
        const half8* s = (const half8*)(WT + (size_t)r * NF + c0);
        half8* d = (half8*)&wlds[r][c0];
        #pragma unroll
        for (int j = 0; j < 4; j++) d[j] = s[j];
    }
    __syncthreads();

    const int wave = tid >> 6, lane = tid & 63;
    const int quad = lane >> 4, l15 = lane & 15;
    const int rowA = bid * 128 + wave * 16 + l15;
    const int rowc = (rowA < M) ? rowA : (M - 1);

    half8 afr[4];
    if (F32IN) {
        const float* X = (const float*)Xv;
        #pragma unroll
        for (int kc = 0; kc < 4; kc++) {
            const floatx4* p = (const floatx4*)(X + (size_t)rowc * NF + kc * 32 + quad * 8);
            floatx4 u = p[0], v = p[1];
            half8 a;
            a[0] = (_Float16)u[0]; a[1] = (_Float16)u[1];
            a[2] = (_Float16)u[2]; a[3] = (_Float16)u[3];
            a[4] = (_Float16)v[0]; a[5] = (_Float16)v[1];
            a[6] = (_Float16)v[2]; a[7] = (_Float16)v[3];
            afr[kc] = a;
        }
    } else {
        const __half* X = (const __half*)Xv;
        #pragma unroll
        for (int kc = 0; kc < 4; kc++)
            afr[kc] = *(const half8*)(X + (size_t)rowc * NF + kc * 32 + quad * 8);
    }

    floatx4 acc[8];
    #pragma unroll
    for (int ct = 0; ct < 8; ct++) { floatx4 z = {0.f, 0.f, 0.f, 0.f}; acc[ct] = z; }

    #pragma unroll
    for (int kc = 0; kc < 4; kc++) {
        #pragma unroll
        for (int ct = 0; ct < 8; ct++) {
            half8 b = *(const half8*)&wlds[ct * 16 + l15][kc * 32 + quad * 8];
            acc[ct] = __builtin_amdgcn_mfma_f32_16x16x32_f16(afr[kc], b, acc[ct], 0, 0, 0);
        }
    }

    const int orow0 = bid * 128 + wave * 16 + quad * 4;
    #pragma unroll
    for (int r = 0; r < 4; r++) {
        int orow = orow0 + r;
        if (orow < M) {
            float s = dinv[orow];
            #pragma unroll
            for (int ct = 0; ct < 8; ct++)
                out[(size_t)orow * NF + ct * 16 + l15] = __float2half(acc[ct][r] * s);
        }
    }
}

// ---------------- mid_k: fused gemm1 + fill (+add_off) ---------------------------
__global__ __launch_bounds__(512) void mid_k(
    const int* __restrict__ src, const int* __restrict__ dst,
    const int* __restrict__ rowptr, const unsigned char* __restrict__ coff,
    const int* __restrict__ blocksum, int* __restrict__ rowptr2,
    int* __restrict__ csr, int E, int N, int Ec, int nb,
    const float* __restrict__ X, const __half* __restrict__ WT,
    const float* __restrict__ dinv, __half* __restrict__ H, int GB2)
{
    __shared__ __align__(16) char smem[NPMAX * 4 + 1024];   // 51.2KB union
    const int tid = threadIdx.x;
    if ((int)blockIdx.x < GB2) {
        gemm_body512<true>(X, WT, dinv, H, N, blockIdx.x, (__half(*)[136])smem);
        return;
    }
    int* lcur = (int*)smem;
    int* pref = (int*)(smem + NPMAX * 4);

    const int b = blockIdx.x - GB2;
    const int p = b & 3, c = b >> 2;
    const int Np = (N + 3) >> 2;
    const int lo = p * Np, hi = min(lo + Np, N);
    const int sz = hi - lo;

    // exclusive prefix of blocksum[0..nb) in pref
    int v = (tid < nb) ? blocksum[tid] : 0;
    if (tid < 256) pref[tid] = v;
    __syncthreads();
    #pragma unroll
    for (int d = 1; d < 256; d <<= 1) {
        int t = (tid < 256 && tid >= d) ? pref[tid - d] : 0;
        __syncthreads();
        if (tid < 256) pref[tid] += t;
        __syncthreads();
    }
    if (tid < 256) pref[tid] -= v;
    __syncthreads();

    for (int i = tid; i < sz; i += 512) {
        int bin = lo + i;
        int r = rowptr[bin] + pref[bin >> 8] + (int)coff[(size_t)c * N + bin];
        lcur[i] = r;
        if (c == 0) rowptr2[bin] = r;
    }
    if (c == 0 && p == 0 && tid == 0) rowptr2[N] = E;
    __syncthreads();

    const int e0 = c * Ec, e1 = min(e0 + Ec, E);
    for (int e = e0 + tid * 4; e + 3 < e1; e += 512 * 4) {
        int4 d = *(const int4*)(dst + e);
        int4 s = *(const int4*)(src + e);
        if (d.x >= lo && d.x < hi) csr[atomicAdd(&lcur[d.x - lo], 1)] = s.x;
        if (d.y >= lo && d.y < hi) csr[atomicAdd(&lcur[d.y - lo], 1)] = s.y;
        if (d.z >= lo && d.z < hi) csr[atomicAdd(&lcur[d.z - lo], 1)] = s.z;
        if (d.w >= lo && d.w < hi) csr[atomicAdd(&lcur[d.w - lo], 1)] = s.w;
    }
    int rem0 = e0 + ((e1 - e0) & ~3);
    for (int e = rem0 + tid; e < e1; e += 512) {
        int d = dst[e];
        if (d >= lo && d < hi) csr[atomicAdd(&lcur[d - lo], 1)] = src[e];
    }
}

// ---------------- gather: wave/node, 2 rows/instr, 32 edges per iter (16 deep) ---
__device__ __forceinline__ floatx4 gather_acc(
    const half4v* __restrict__ hs4, const int* __restrict__ csr,
    int base, int cnt, int node, int eg, int fl, int lane)
{
    floatx4 acc = {0.f, 0.f, 0.f, 0.f};
    if (eg == 0) {   // self-loop
        half4v s = hs4[(size_t)node * 32 + fl];
        acc[0] = (float)s[0]; acc[1] = (float)s[1];
        acc[2] = (float)s[2]; acc[3] = (float)s[3];
    }
    for (int off = 0; off < cnt; off += 64) {
        int m = min(64, cnt - off);
        int idx = 0;
        if (lane < m) idx = __builtin_nontemporal_load(&csr[base + off + lane]);
        for (int j = 0; j < m; j += 32) {   // 32 edges, 16 loads in flight
            int s[16];
            half4v v[16];
            #pragma unroll
            for (int t = 0; t < 16; t++)
                s[t] = __shfl(idx, min(j + 2 * t + eg, m - 1), 64);
            #pragma unroll
            for (int t = 0; t < 16; t++)
                v[t] = hs4[(size_t)s[t] * 32 + fl];
            #pragma unroll
            for (int t = 0; t < 16; t++) {
                if (j + 2 * t + eg < m) {
                    acc[0] += (float)v[t][0]; acc[1] += (float)v[t][1];
                    acc[2] += (float)v[t][2]; acc[3] += (float)v[t][3];
                }
            }
        }
    }
    #pragma unroll
    for (int k = 0; k < 4; k++) acc[k] += __shfl_xor(acc[k], 32, 64);
    return acc;
}

// ---------------- aggemm: fused agg1 (+bias+relu) + gemm2 ------------------------
// Block = 16 nodes = one MFMA M-tile. 4 waves gather 4 nodes each into LDS
// arow[16][136] (post relu, fp16); sync; each wave MFMAs 2 column-tiles of
// H2[node] = dinv[node] * (arow @ W2). Kills the A16 write+read (25.6MB) and
// one launch. WT2 staged in LDS (34.8KB) + arow 4.3KB -> 4 blocks/CU.
__global__ __launch_bounds__(256) void aggemm_k(
    const __half* __restrict__ hs, const int* __restrict__ rowptr,
    const int* __restrict__ csr, const float* __restrict__ dinv,
    const float* __restrict__ bias, const __half* __restrict__ WT2,
    __half* __restrict__ H2, int n)
{
    __shared__ __half wlds[128][136];
    __shared__ __half arow[16][136];
    const int tid = threadIdx.x;
    {   // stage WT2: 2 threads/row, 64 halves each
        int r = tid >> 1, c0 = (tid & 1) * 64;
        const half8* s = (const half8*)(WT2 + (size_t)r * NF + c0);
        half8* d = (half8*)&wlds[r][c0];
        #pragma unroll
        for (int j = 0; j < 8; j++) d[j] = s[j];
    }

    const int wave = tid >> 6, lane = tid & 63;
    const int eg = lane >> 5, fl = lane & 31;
    const half4v* hs4 = (const half4v*)hs;

    #pragma unroll
    for (int u = 0; u < 4; u++) {
        int node = blockIdx.x * 16 + wave * 4 + u;
        if (node < n) {
            int base = rowptr[node];
            int cnt  = rowptr[node + 1] - base;
            floatx4 acc = gather_acc(hs4, csr, base, cnt, node, eg, fl, lane);
            if (eg == 0) {
                float dv = dinv[node];
                half4v h;
                h[0] = (_Float16)fmaxf(dv * acc[0] + bias[fl * 4 + 0], 0.f);
                h[1] = (_Float16)fmaxf(dv * acc[1] + bias[fl * 4 + 1], 0.f);
                h[2] = (_Float16)fmaxf(dv * acc[2] + bias[fl * 4 + 2], 0.f);
                h[3] = (_Float16)fmaxf(dv * acc[3] + bias[fl * 4 + 3], 0.f);
                *(half4v*)&arow[wave * 4 + u][fl * 4] = h;
            }
        } else if (eg == 0) {
            half4v z = {(_Float16)0.f, (_Float16)0.f, (_Float16)0.f, (_Float16)0.f};
            *(half4v*)&arow[wave * 4 + u][fl * 4] = z;
        }
    }
    __syncthreads();

    // MFMA: A = arow (16 rows), each wave does column-tiles ct=wave*2, wave*2+1
    const int quad = lane >> 4, l15 = lane & 15;
    half8 afr[4];
    #pragma unroll
    for (int kc = 0; kc < 4; kc++)
        afr[kc] = *(const half8*)&arow[l15][kc * 32 + quad * 8];

    floatx4 acc0 = {0.f, 0.f, 0.f, 0.f}, acc1 = {0.f, 0.f, 0.f, 0.f};
    const int ct0 = wave * 2, ct1 = wave * 2 + 1;
    #pragma unroll
    for (int kc = 0; kc < 4; kc++) {
        half8 b0 = *(const half8*)&wlds[ct0 * 16 + l15][kc * 32 + quad * 8];
        half8 b1 = *(const half8*)&wlds[ct1 * 16 + l15][kc * 32 + quad * 8];
        acc0 = __builtin_amdgcn_mfma_f32_16x16x32_f16(afr[kc], b0, acc0, 0, 0, 0);
        acc1 = __builtin_amdgcn_mfma_f32_16x16x32_f16(afr[kc], b1, acc1, 0, 0, 0);
    }
    #pragma unroll
    for (int r = 0; r < 4; r++) {
        int node = blockIdx.x * 16 + quad * 4 + r;
        if (node < n) {
            float s = dinv[node];
            H2[(size_t)node * NF + ct0 * 16 + l15] = __float2half(acc0[r] * s);
            H2[(size_t)node * NF + ct1 * 16 + l15] = __float2half(acc1[r] * s);
        }
    }
}

// ---------------- agg2: final aggregation, fp32 output ---------------------------
__global__ __launch_bounds__(256) void agg2_k(
    const __half* __restrict__ hs, const int* __restrict__ rowptr,
    const int* __restrict__ csr, const float* __restrict__ dinv,
    const float* __restrict__ bias, float* __restrict__ outf, int n)
{
    int wave = threadIdx.x >> 6;
    int lane = threadIdx.x & 63;
    int node = blockIdx.x * 4 + wave;
    if (node >= n) return;
    const int eg = lane >> 5, fl = lane & 31;

    int base = rowptr[node];
    int cnt  = rowptr[node + 1] - base;
    floatx4 acc = gather_acc((const half4v*)hs, csr, base, cnt, node, eg, fl, lane);

    if (eg == 0) {
        float dv = dinv[node];
        floatx4 w;
        w[0] = dv * acc[0] + bias[fl * 4 + 0];
        w[1] = dv * acc[1] + bias[fl * 4 + 1];
        w[2] = dv * acc[2] + bias[fl * 4 + 2];
        w[3] = dv * acc[3] + bias[fl * 4 + 3];
        *(floatx4*)(outf + (size_t)node * NF + fl * 4) = w;
    }
}

// ---------------- launch ----------------

extern "C" void kernel_launch(void* const* d_in, const int* in_sizes, int n_in,
                              void* d_out, int out_size, void* d_ws, size_t ws_size,
                              hipStream_t stream) {
    const float* x  = (const float*)d_in[0];
    const int*   ei = (const int*)d_in[1];
    const float* W1 = (const float*)d_in[2];
    const float* b1 = (const float*)d_in[3];
    const float* W2 = (const float*)d_in[4];
    const float* b2 = (const float*)d_in[5];
    float* out = (float*)d_out;

    const int N = in_sizes[0] / NF;   // 50000
    const int E = in_sizes[1] / 2;    // 800000
    const int* src = ei;
    const int* dst = ei + E;

    char* ws = (char*)d_ws;
    size_t off = 0;
    auto alloc = [&](size_t bytes) {
        void* p = ws + off;
        off += bytes;
        off = (off + 63) & ~(size_t)63;
        return p;
    };
    unsigned char* pcnt = (unsigned char*)alloc((size_t)KC * N);  // counts->coff
    int*    rowptr  = (int*)alloc((size_t)(N + 1) * 4);   // local prefixes
    int*    rowptr2 = (int*)alloc((size_t)(N + 1) * 4);   // corrected (agg uses)
    int*    csr     = (int*)alloc((size_t)E * 4);
    float*  dinv    = (float*)alloc((size_t)N * 4);
    int*    bsum    = (int*)alloc((size_t)256 * 4);
    __half* WT1     = (__half*)alloc((size_t)NF * NF * 2);
    __half* WT2     = (__half*)alloc((size_t)NF * NF * 2);
    __half* H16     = (__half*)alloc((size_t)N * NF * 2);
    __half* H2      = (__half*)alloc((size_t)N * NF * 2);

    int nb  = (N + 255) / 256;                 // 196 (<=256)
    int Ec  = (((E + KC - 1) / KC) + 3) & ~3;  // chunk size, multiple of 4
    int GB2 = (N + 127) / 128;                 // gemm1 blocks (512 thr)
    int ag1 = (N + 15) / 16;                   // fused agg1+gemm2 blocks
    int ab  = (N + 3) / 4;

    count2_k<<<KC * NPART, 512, 0, stream>>>(dst, pcnt, E, N, Ec);
    pscan2_k<<<nb + 128, 256, 0, stream>>>(pcnt, dinv, rowptr, bsum, N, N, nb,
                                           W1, W2, WT1, WT2);
    mid_k<<<GB2 + KC * NPART, 512, 0, stream>>>(src, dst, rowptr, pcnt, bsum,
                                                rowptr2, csr, E, N, Ec, nb,
                                                x, WT1, dinv, H16, GB2);
    aggemm_k<<<ag1, 256, 0, stream>>>(H16, rowptr2, csr, dinv, b1, WT2, H2, N);
    agg2_k<<<ab, 256, 0, stream>>>(H2, rowptr2, csr, dinv, b2, out, N);
}

// Round 15
// 217.527 us; speedup vs baseline: 1.0265x; 1.0265x over previous
//
#include <hip/hip_runtime.h>
#include <hip/hip_fp16.h>

#define NF 128    // feature dim, fixed by the problem
#define KC 64     // edge chunks
#define NPART 4   // node partitions (N/4 ints must fit LDS: 12500*4B = 50KB)
#define NPMAX 12544

typedef _Float16 half8  __attribute__((ext_vector_type(8)));
typedef _Float16 half4v __attribute__((ext_vector_type(4)));
typedef float    floatx4 __attribute__((ext_vector_type(4)));

// ---------------- count2: LDS histogram per (chunk, partition) -------------------
// Block b: partition p=b&3, chunk c=b>>2. Zero global atomics. pcnt is uint8
// (per-chunk counts <=~10 << 255).
__global__ __launch_bounds__(512) void count2_k(
    const int* __restrict__ dst, unsigned char* __restrict__ pcnt,
    int E, int N, int Ec)
{
    __shared__ int lcnt[NPMAX];
    const int p = blockIdx.x & 3, c = blockIdx.x >> 2;
    const int Np = (N + 3) >> 2;
    const int lo = p * Np, hi = min(lo + Np, N);
    const int sz = hi - lo;
    for (int i = threadIdx.x; i < sz; i += 512) lcnt[i] = 0;
    __syncthreads();

    const int e0 = c * Ec, e1 = min(e0 + Ec, E);
    for (int e = e0 + (int)threadIdx.x * 4; e + 3 < e1; e += 512 * 4) {
        int4 d = *(const int4*)(dst + e);
        if (d.x >= lo && d.x < hi) atomicAdd(&lcnt[d.x - lo], 1);
        if (d.y >= lo && d.y < hi) atomicAdd(&lcnt[d.y - lo], 1);
        if (d.z >= lo && d.z < hi) atomicAdd(&lcnt[d.z - lo], 1);
        if (d.w >= lo && d.w < hi) atomicAdd(&lcnt[d.w - lo], 1);
    }
    int rem0 = e0 + ((e1 - e0) & ~3);
    for (int e = rem0 + (int)threadIdx.x; e < e1; e += 512) {
        int d = dst[e];
        if (d >= lo && d < hi) atomicAdd(&lcnt[d - lo], 1);
    }
    __syncthreads();
    for (int i = threadIdx.x; i < sz; i += 512)
        pcnt[(size_t)c * N + lo + i] = (unsigned char)lcnt[i];
}

// ---------------- pscan2 (+fused W-transpose) ------------------------------------
__global__ __launch_bounds__(256) void pscan2_k(
    unsigned char* __restrict__ pcnt, float* __restrict__ dinv,
    int* __restrict__ rowptr, int* __restrict__ blocksum, int n, int N, int nb,
    const float* __restrict__ W1, const float* __restrict__ W2,
    __half* __restrict__ WT1, __half* __restrict__ WT2)
{
    if ((int)blockIdx.x >= nb) {
        int idx = ((int)blockIdx.x - nb) * 256 + threadIdx.x;   // 0..32767
        const float* W = (idx < 16384) ? W1 : W2;
        __half* WT     = (idx < 16384) ? WT1 : WT2;
        int j = idx & 16383;
        int nn = j & 127, k = j >> 7;
        WT[nn * NF + k] = __float2half(W[k * NF + nn]);
        return;
    }
    __shared__ int sm[256];
    int tid = threadIdx.x;
    int bin = blockIdx.x * 256 + tid;
    int total = 0;
    if (bin < n) {
        #pragma unroll 4
        for (int c = 0; c < KC; c++) {
            size_t o = (size_t)c * N + bin;
            int v = pcnt[o];
            pcnt[o] = (unsigned char)total;   // exclusive chunk prefix (coff)
            total += v;
        }
        dinv[bin] = rsqrtf((float)total + 1.0f);  // +1 = self-loop
    }
    sm[tid] = total;
    __syncthreads();
    #pragma unroll
    for (int d = 1; d < 256; d <<= 1) {
        int t = (tid >= d) ? sm[tid - d] : 0;
        __syncthreads();
        sm[tid] += t;
        __syncthreads();
    }
    if (bin < n) rowptr[bin] = sm[tid] - total;    // local exclusive prefix
    if (tid == 255) blocksum[blockIdx.x] = sm[255];
}

// ---------------- MFMA GEMM body (512 threads, 128 rows/block) -------------------
template<bool F32IN>
__device__ __forceinline__ void gemm_body512(
    const void* __restrict__ Xv, const __half* __restrict__ WT,
    const float* __restrict__ dinv, __half* __restrict__ out, int M, int bid,
    __half (*wlds)[136])
{
    const int tid = threadIdx.x;
    {   // stage WT (128x128 halves): 4 threads/row, 32 halves each
        int r = tid >> 2;
        int c0 = (tid & 3) * 32;
        const half8* s = (const half8*)(WT + (size_t)r * NF + c0);
        half8* d = (half8*)&wlds[r][c0];
        #pragma unroll
        for (int j = 0; j < 4; j++) d[j] = s[j];
    }
    __syncthreads();

    const int wave = tid >> 6, lane = tid & 63;
    const int quad = lane >> 4, l15 = lane & 15;
    const int rowA = bid * 128 + wave * 16 + l15;
    const int rowc = (rowA < M) ? rowA : (M - 1);

    half8 afr[4];
    if (F32IN) {
        const float* X = (const float*)Xv;
        #pragma unroll
        for (int kc = 0; kc < 4; kc++) {
            const floatx4* p = (const floatx4*)(X + (size_t)rowc * NF + kc * 32 + quad * 8);
            floatx4 u = p[0], v = p[1];
            half8 a;
            a[0] = (_Float16)u[0]; a[1] = (_Float16)u[1];
            a[2] = (_Float16)u[2]; a[3] = (_Float16)u[3];
            a[4] = (_Float16)v[0]; a[5] = (_Float16)v[1];
            a[6] = (_Float16)v[2]; a[7] = (_Float16)v[3];
            afr[kc] = a;
        }
    } else {
        const __half* X = (const __half*)Xv;
        #pragma unroll
        for (int kc = 0; kc < 4; kc++)
            afr[kc] = *(const half8*)(X + (size_t)rowc * NF + kc * 32 + quad * 8);
    }

    floatx4 acc[8];
    #pragma unroll
    for (int ct = 0; ct < 8; ct++) { floatx4 z = {0.f, 0.f, 0.f, 0.f}; acc[ct] = z; }

    #pragma unroll
    for (int kc = 0; kc < 4; kc++) {
        #pragma unroll
        for (int ct = 0; ct < 8; ct++) {
            half8 b = *(const half8*)&wlds[ct * 16 + l15][kc * 32 + quad * 8];
            acc[ct] = __builtin_amdgcn_mfma_f32_16x16x32_f16(afr[kc], b, acc[ct], 0, 0, 0);
        }
    }

    const int orow0 = bid * 128 + wave * 16 + quad * 4;
    #pragma unroll
    for (int r = 0; r < 4; r++) {
        int orow = orow0 + r;
        if (orow < M) {
            float s = dinv[orow];
            #pragma unroll
            for (int ct = 0; ct < 8; ct++)
                out[(size_t)orow * NF + ct * 16 + l15] = __float2half(acc[ct][r] * s);
        }
    }
}

// ---------------- mid_k: fused gemm1 + fill (+add_off) ---------------------------
__global__ __launch_bounds__(512) void mid_k(
    const int* __restrict__ src, const int* __restrict__ dst,
    const int* __restrict__ rowptr, const unsigned char* __restrict__ coff,
    const int* __restrict__ blocksum, int* __restrict__ rowptr2,
    int* __restrict__ csr, int E, int N, int Ec, int nb,
    const float* __restrict__ X, const __half* __restrict__ WT,
    const float* __restrict__ dinv, __half* __restrict__ H, int GB2)
{
    __shared__ __align__(16) char smem[NPMAX * 4 + 1024];   // 51.2KB union
    const int tid = threadIdx.x;
    if ((int)blockIdx.x < GB2) {
        gemm_body512<true>(X, WT, dinv, H, N, blockIdx.x, (__half(*)[136])smem);
        return;
    }
    int* lcur = (int*)smem;
    int* pref = (int*)(smem + NPMAX * 4);

    const int b = blockIdx.x - GB2;
    const int p = b & 3, c = b >> 2;
    const int Np = (N + 3) >> 2;
    const int lo = p * Np, hi = min(lo + Np, N);
    const int sz = hi - lo;

    // exclusive prefix of blocksum[0..nb) in pref
    int v = (tid < nb) ? blocksum[tid] : 0;
    if (tid < 256) pref[tid] = v;
    __syncthreads();
    #pragma unroll
    for (int d = 1; d < 256; d <<= 1) {
        int t = (tid < 256 && tid >= d) ? pref[tid - d] : 0;
        __syncthreads();
        if (tid < 256) pref[tid] += t;
        __syncthreads();
    }
    if (tid < 256) pref[tid] -= v;
    __syncthreads();

    for (int i = tid; i < sz; i += 512) {
        int bin = lo + i;
        int r = rowptr[bin] + pref[bin >> 8] + (int)coff[(size_t)c * N + bin];
        lcur[i] = r;
        if (c == 0) rowptr2[bin] = r;
    }
    if (c == 0 && p == 0 && tid == 0) rowptr2[N] = E;
    __syncthreads();

    const int e0 = c * Ec, e1 = min(e0 + Ec, E);
    for (int e = e0 + tid * 4; e + 3 < e1; e += 512 * 4) {
        int4 d = *(const int4*)(dst + e);
        int4 s = *(const int4*)(src + e);
        if (d.x >= lo && d.x < hi) csr[atomicAdd(&lcur[d.x - lo], 1)] = s.x;
        if (d.y >= lo && d.y < hi) csr[atomicAdd(&lcur[d.y - lo], 1)] = s.y;
        if (d.z >= lo && d.z < hi) csr[atomicAdd(&lcur[d.z - lo], 1)] = s.z;
        if (d.w >= lo && d.w < hi) csr[atomicAdd(&lcur[d.w - lo], 1)] = s.w;
    }
    int rem0 = e0 + ((e1 - e0) & ~3);
    for (int e = rem0 + tid; e < e1; e += 512) {
        int d = dst[e];
        if (d >= lo && d < hi) csr[atomicAdd(&lcur[d - lo], 1)] = src[e];
    }
}

// ---------------- gemm2 (standalone, 256 thr / 64 rows — proven R8 shape) --------
__global__ __launch_bounds__(256) void gemm2_k(
    const __half* __restrict__ A, const __half* __restrict__ WT,
    const float* __restrict__ dinv, __half* __restrict__ H, int M)
{
    __shared__ __half wlds[128][136];
    const int tid = threadIdx.x;
    {
        int r = tid >> 1, c0 = (tid & 1) * 64;
        const half8* s = (const half8*)(WT + (size_t)r * NF + c0);
        half8* d = (half8*)&wlds[r][c0];
        #pragma unroll
        for (int j = 0; j < 8; j++) d[j] = s[j];
    }
    __syncthreads();

    const int wave = tid >> 6, lane = tid & 63;
    const int quad = lane >> 4, l15 = lane & 15;
    const int rowA = blockIdx.x * 64 + wave * 16 + l15;
    const int rowc = (rowA < M) ? rowA : (M - 1);

    half8 afr[4];
    #pragma unroll
    for (int kc = 0; kc < 4; kc++)
        afr[kc] = *(const half8*)(A + (size_t)rowc * NF + kc * 32 + quad * 8);

    floatx4 acc[8];
    #pragma unroll
    for (int ct = 0; ct < 8; ct++) { floatx4 z = {0.f, 0.f, 0.f, 0.f}; acc[ct] = z; }

    #pragma unroll
    for (int kc = 0; kc < 4; kc++) {
        #pragma unroll
        for (int ct = 0; ct < 8; ct++) {
            half8 b = *(const half8*)&wlds[ct * 16 + l15][kc * 32 + quad * 8];
            acc[ct] = __builtin_amdgcn_mfma_f32_16x16x32_f16(afr[kc], b, acc[ct], 0, 0, 0);
        }
    }

    const int orow0 = blockIdx.x * 64 + wave * 16 + quad * 4;
    #pragma unroll
    for (int r = 0; r < 4; r++) {
        int orow = orow0 + r;
        if (orow < M) {
            float s = dinv[orow];
            #pragma unroll
            for (int ct = 0; ct < 8; ct++)
                H[(size_t)orow * NF + ct * 16 + l15] = __float2half(acc[ct][r] * s);
        }
    }
}

// ---------------- gather: wave/node, 2 rows/instr, 32 edges/iter (16 deep) -------
// csr index load issued FIRST (independent) so the dependent shfl->gather chain
// overlaps the self-row load. Gather kernels stay 0-LDS (R14 lesson: LDS in the
// latency-bound gather halves occupancy and ~doubles time).
__device__ __forceinline__ floatx4 gather_acc(
    const half4v* __restrict__ hs4, const int* __restrict__ csr,
    int base, int cnt, int node, int eg, int fl, int lane)
{
    floatx4 acc = {0.f, 0.f, 0.f, 0.f};
    int m0 = min(64, cnt);
    int idx0 = 0;
    if (lane < m0) idx0 = __builtin_nontemporal_load(&csr[base + lane]);  // first
    if (eg == 0) {   // self-loop
        half4v s = hs4[(size_t)node * 32 + fl];
        acc[0] = (float)s[0]; acc[1] = (float)s[1];
        acc[2] = (float)s[2]; acc[3] = (float)s[3];
    }
    for (int off = 0; off < cnt; off += 64) {
        int m = min(64, cnt - off);
        int idx = (off == 0) ? idx0 : 0;
        if (off && lane < m) idx = __builtin_nontemporal_load(&csr[base + off + lane]);
        for (int j = 0; j < m; j += 32) {   // 32 edges, 16 loads in flight
            int s[16];
            half4v v[16];
            #pragma unroll
            for (int t = 0; t < 16; t++)
                s[t] = __shfl(idx, min(j + 2 * t + eg, m - 1), 64);
            #pragma unroll
            for (int t = 0; t < 16; t++)
                v[t] = hs4[(size_t)s[t] * 32 + fl];
            #pragma unroll
            for (int t = 0; t < 16; t++) {
                if (j + 2 * t + eg < m) {
                    acc[0] += (float)v[t][0]; acc[1] += (float)v[t][1];
                    acc[2] += (float)v[t][2]; acc[3] += (float)v[t][3];
                }
            }
        }
    }
    #pragma unroll
    for (int k = 0; k < 4; k++) acc[k] += __shfl_xor(acc[k], 32, 64);
    return acc;
}

// ---------------- agg: wave/node; outh fp16+relu (layer 1) or outf fp32 ----------
__global__ __launch_bounds__(256) void agg_k(
    const __half* __restrict__ hs, const int* __restrict__ rowptr,
    const int* __restrict__ csr, const float* __restrict__ dinv,
    const float* __restrict__ bias, __half* __restrict__ outh,
    float* __restrict__ outf, int n)
{
    int wave = threadIdx.x >> 6;
    int lane = threadIdx.x & 63;
    int node = blockIdx.x * 4 + wave;
    if (node >= n) return;
    const int eg = lane >> 5, fl = lane & 31;

    int base = rowptr[node];
    int cnt  = rowptr[node + 1] - base;
    floatx4 acc = gather_acc((const half4v*)hs, csr, base, cnt, node, eg, fl, lane);

    if (eg == 0) {
        float dv = dinv[node];
        float o0 = dv * acc[0] + bias[fl * 4 + 0];
        float o1 = dv * acc[1] + bias[fl * 4 + 1];
        float o2 = dv * acc[2] + bias[fl * 4 + 2];
        float o3 = dv * acc[3] + bias[fl * 4 + 3];
        if (outh) {
            half4v h;
            h[0] = (_Float16)fmaxf(o0, 0.f); h[1] = (_Float16)fmaxf(o1, 0.f);
            h[2] = (_Float16)fmaxf(o2, 0.f); h[3] = (_Float16)fmaxf(o3, 0.f);
            *(half4v*)&outh[(size_t)node * NF + fl * 4] = h;
        } else {
            floatx4 w = {o0, o1, o2, o3};
            *(floatx4*)(outf + (size_t)node * NF + fl * 4) = w;
        }
    }
}

// ---------------- launch ----------------

extern "C" void kernel_launch(void* const* d_in, const int* in_sizes, int n_in,
                              void* d_out, int out_size, void* d_ws, size_t ws_size,
                              hipStream_t stream) {
    const float* x  = (const float*)d_in[0];
    const int*   ei = (const int*)d_in[1];
    const float* W1 = (const float*)d_in[2];
    const float* b1 = (const float*)d_in[3];
    const float* W2 = (const float*)d_in[4];
    const float* b2 = (const float*)d_in[5];
    float* out = (float*)d_out;

    const int N = in_sizes[0] / NF;   // 50000
    const int E = in_sizes[1] / 2;    // 800000
    const int* src = ei;
    const int* dst = ei + E;

    char* ws = (char*)d_ws;
    size_t off = 0;
    auto alloc = [&](size_t bytes) {
        void* p = ws + off;
        off += bytes;
        off = (off + 63) & ~(size_t)63;
        return p;
    };
    unsigned char* pcnt = (unsigned char*)alloc((size_t)KC * N);  // counts->coff
    int*    rowptr  = (int*)alloc((size_t)(N + 1) * 4);   // local prefixes
    int*    rowptr2 = (int*)alloc((size_t)(N + 1) * 4);   // corrected (agg uses)
    int*    csr     = (int*)alloc((size_t)E * 4);
    float*  dinv    = (float*)alloc((size_t)N * 4);
    int*    bsum    = (int*)alloc((size_t)256 * 4);
    __half* WT1     = (__half*)alloc((size_t)NF * NF * 2);
    __half* WT2     = (__half*)alloc((size_t)NF * NF * 2);
    __half* H16     = (__half*)alloc((size_t)N * NF * 2);
    __half* A16     = (__half*)alloc((size_t)N * NF * 2);

    int nb  = (N + 255) / 256;                 // 196 (<=256)
    int Ec  = (((E + KC - 1) / KC) + 3) & ~3;  // chunk size, multiple of 4
    int GB2 = (N + 127) / 128;                 // gemm1 blocks (512 thr)
    int gb  = (N + 63) / 64;
    int ab  = (N + 3) / 4;

    count2_k<<<KC * NPART, 512, 0, stream>>>(dst, pcnt, E, N, Ec);
    pscan2_k<<<nb + 128, 256, 0, stream>>>(pcnt, dinv, rowptr, bsum, N, N, nb,
                                           W1, W2, WT1, WT2);
    mid_k<<<GB2 + KC * NPART, 512, 0, stream>>>(src, dst, rowptr, pcnt, bsum,
                                                rowptr2, csr, E, N, Ec, nb,
                                                x, WT1, dinv, H16, GB2);
    agg_k<<<ab, 256, 0, stream>>>(H16, rowptr2, csr, dinv, b1, A16, nullptr, N);
    gemm2_k<<<gb, 256, 0, stream>>>(A16, WT2, dinv, H16, N);
    agg_k<<<ab, 256, 0, stream>>>(H16, rowptr2, csr, dinv, b2, nullptr, out, N);
}

// Round 16
// 207.082 us; speedup vs baseline: 1.0782x; 1.0504x over previous
//
#include <hip/hip_runtime.h>
#include <hip/hip_fp16.h>

#define NF 128    // feature dim, fixed by the problem
#define KC 64     // edge chunks
#define NPART 4   // node partitions (N/4 ints must fit LDS: 12500*4B = 50KB)
#define NPMAX 12544

typedef _Float16 half8  __attribute__((ext_vector_type(8)));
typedef _Float16 half4v __attribute__((ext_vector_type(4)));
typedef float    floatx4 __attribute__((ext_vector_type(4)));

// ---------------- count2: LDS histogram per (chunk, partition) -------------------
// Block b: partition p=b&3, chunk c=b>>2. Zero global atomics. pcnt is uint8
// (per-chunk counts <=~10 << 255).
__global__ __launch_bounds__(512) void count2_k(
    const int* __restrict__ dst, unsigned char* __restrict__ pcnt,
    int E, int N, int Ec)
{
    __shared__ int lcnt[NPMAX];
    const int p = blockIdx.x & 3, c = blockIdx.x >> 2;
    const int Np = (N + 3) >> 2;
    const int lo = p * Np, hi = min(lo + Np, N);
    const int sz = hi - lo;
    for (int i = threadIdx.x; i < sz; i += 512) lcnt[i] = 0;
    __syncthreads();

    const int e0 = c * Ec, e1 = min(e0 + Ec, E);
    for (int e = e0 + (int)threadIdx.x * 4; e + 3 < e1; e += 512 * 4) {
        int4 d = *(const int4*)(dst + e);
        if (d.x >= lo && d.x < hi) atomicAdd(&lcnt[d.x - lo], 1);
        if (d.y >= lo && d.y < hi) atomicAdd(&lcnt[d.y - lo], 1);
        if (d.z >= lo && d.z < hi) atomicAdd(&lcnt[d.z - lo], 1);
        if (d.w >= lo && d.w < hi) atomicAdd(&lcnt[d.w - lo], 1);
    }
    int rem0 = e0 + ((e1 - e0) & ~3);
    for (int e = rem0 + (int)threadIdx.x; e < e1; e += 512) {
        int d = dst[e];
        if (d >= lo && d < hi) atomicAdd(&lcnt[d - lo], 1);
    }
    __syncthreads();
    for (int i = threadIdx.x; i < sz; i += 512)
        pcnt[(size_t)c * N + lo + i] = (unsigned char)lcnt[i];
}

// ---------------- pscan2 (+fused W-transpose) ------------------------------------
__global__ __launch_bounds__(256) void pscan2_k(
    unsigned char* __restrict__ pcnt, float* __restrict__ dinv,
    int* __restrict__ rowptr, int* __restrict__ blocksum, int n, int N, int nb,
    const float* __restrict__ W1, const float* __restrict__ W2,
    __half* __restrict__ WT1, __half* __restrict__ WT2)
{
    if ((int)blockIdx.x >= nb) {
        int idx = ((int)blockIdx.x - nb) * 256 + threadIdx.x;   // 0..32767
        const float* W = (idx < 16384) ? W1 : W2;
        __half* WT     = (idx < 16384) ? WT1 : WT2;
        int j = idx & 16383;
        int nn = j & 127, k = j >> 7;
        WT[nn * NF + k] = __float2half(W[k * NF + nn]);
        return;
    }
    __shared__ int sm[256];
    int tid = threadIdx.x;
    int bin = blockIdx.x * 256 + tid;
    int total = 0;
    if (bin < n) {
        #pragma unroll 4
        for (int c = 0; c < KC; c++) {
            size_t o = (size_t)c * N + bin;
            int v = pcnt[o];
            pcnt[o] = (unsigned char)total;   // exclusive chunk prefix (coff)
            total += v;
        }
        dinv[bin] = rsqrtf((float)total + 1.0f);  // +1 = self-loop
    }
    sm[tid] = total;
    __syncthreads();
    #pragma unroll
    for (int d = 1; d < 256; d <<= 1) {
        int t = (tid >= d) ? sm[tid - d] : 0;
        __syncthreads();
        sm[tid] += t;
        __syncthreads();
    }
    if (bin < n) rowptr[bin] = sm[tid] - total;    // local exclusive prefix
    if (tid == 255) blocksum[blockIdx.x] = sm[255];
}

// ---------------- MFMA GEMM body (512 threads, 128 rows/block) -------------------
template<bool F32IN>
__device__ __forceinline__ void gemm_body512(
    const void* __restrict__ Xv, const __half* __restrict__ WT,
    const float* __restrict__ dinv, __half* __restrict__ out, int M, int bid,
    __half (*wlds)[136])
{
    const int tid = threadIdx.x;
    {   // stage WT (128x128 halves): 4 threads/row, 32 halves each
        int r = tid >> 2;
        int c0 = (tid & 3) * 32;
        const half8* s = (const half8*)(WT + (size_t)r * NF + c0);
        half8* d = (half8*)&wlds[r][c0];
        #pragma unroll
        for (int j = 0; j < 4; j++) d[j] = s[j];
    }
    __syncthreads();

    const int wave = tid >> 6, lane = tid & 63;
    const int quad = lane >> 4, l15 = lane & 15;
    const int rowA = bid * 128 + wave * 16 + l15;
    const int rowc = (rowA < M) ? rowA : (M - 1);

    half8 afr[4];
    if (F32IN) {
        const float* X = (const float*)Xv;
        #pragma unroll
        for (int kc = 0; kc < 4; kc++) {
            const floatx4* p = (const floatx4*)(X + (size_t)rowc * NF + kc * 32 + quad * 8);
            floatx4 u = p[0], v = p[1];
            half8 a;
            a[0] = (_Float16)u[0]; a[1] = (_Float16)u[1];
            a[2] = (_Float16)u[2]; a[3] = (_Float16)u[3];
            a[4] = (_Float16)v[0]; a[5] = (_Float16)v[1];
            a[6] = (_Float16)v[2]; a[7] = (_Float16)v[3];
            afr[kc] = a;
        }
    } else {
        const __half* X = (const __half*)Xv;
        #pragma unroll
        for (int kc = 0; kc < 4; kc++)
            afr[kc] = *(const half8*)(X + (size_t)rowc * NF + kc * 32 + quad * 8);
    }

    floatx4 acc[8];
    #pragma unroll
    for (int ct = 0; ct < 8; ct++) { floatx4 z = {0.f, 0.f, 0.f, 0.f}; acc[ct] = z; }

    #pragma unroll
    for (int kc = 0; kc < 4; kc++) {
        #pragma unroll
        for (int ct = 0; ct < 8; ct++) {
            half8 b = *(const half8*)&wlds[ct * 16 + l15][kc * 32 + quad * 8];
            acc[ct] = __builtin_amdgcn_mfma_f32_16x16x32_f16(afr[kc], b, acc[ct], 0, 0, 0);
        }
    }

    const int orow0 = bid * 128 + wave * 16 + quad * 4;
    #pragma unroll
    for (int r = 0; r < 4; r++) {
        int orow = orow0 + r;
        if (orow < M) {
            float s = dinv[orow];
            #pragma unroll
            for (int ct = 0; ct < 8; ct++)
                out[(size_t)orow * NF + ct * 16 + l15] = __float2half(acc[ct][r] * s);
        }
    }
}

// ---------------- mid_k: fused gemm1 + fill (+add_off) ---------------------------
__global__ __launch_bounds__(512) void mid_k(
    const int* __restrict__ src, const int* __restrict__ dst,
    const int* __restrict__ rowptr, const unsigned char* __restrict__ coff,
    const int* __restrict__ blocksum, int* __restrict__ rowptr2,
    int* __restrict__ csr, int E, int N, int Ec, int nb,
    const float* __restrict__ X, const __half* __restrict__ WT,
    const float* __restrict__ dinv, __half* __restrict__ H, int GB2)
{
    __shared__ __align__(16) char smem[NPMAX * 4 + 1024];   // 51.2KB union
    const int tid = threadIdx.x;
    if ((int)blockIdx.x < GB2) {
        gemm_body512<true>(X, WT, dinv, H, N, blockIdx.x, (__half(*)[136])smem);
        return;
    }
    int* lcur = (int*)smem;
    int* pref = (int*)(smem + NPMAX * 4);

    const int b = blockIdx.x - GB2;
    const int p = b & 3, c = b >> 2;
    const int Np = (N + 3) >> 2;
    const int lo = p * Np, hi = min(lo + Np, N);
    const int sz = hi - lo;

    // exclusive prefix of blocksum[0..nb) in pref
    int v = (tid < nb) ? blocksum[tid] : 0;
    if (tid < 256) pref[tid] = v;
    __syncthreads();
    #pragma unroll
    for (int d = 1; d < 256; d <<= 1) {
        int t = (tid < 256 && tid >= d) ? pref[tid - d] : 0;
        __syncthreads();
        if (tid < 256) pref[tid] += t;
        __syncthreads();
    }
    if (tid < 256) pref[tid] -= v;
    __syncthreads();

    for (int i = tid; i < sz; i += 512) {
        int bin = lo + i;
        int r = rowptr[bin] + pref[bin >> 8] + (int)coff[(size_t)c * N + bin];
        lcur[i] = r;
        if (c == 0) rowptr2[bin] = r;
    }
    if (c == 0 && p == 0 && tid == 0) rowptr2[N] = E;
    __syncthreads();

    const int e0 = c * Ec, e1 = min(e0 + Ec, E);
    for (int e = e0 + tid * 4; e + 3 < e1; e += 512 * 4) {
        int4 d = *(const int4*)(dst + e);
        int4 s = *(const int4*)(src + e);
        if (d.x >= lo && d.x < hi) csr[atomicAdd(&lcur[d.x - lo], 1)] = s.x;
        if (d.y >= lo && d.y < hi) csr[atomicAdd(&lcur[d.y - lo], 1)] = s.y;
        if (d.z >= lo && d.z < hi) csr[atomicAdd(&lcur[d.z - lo], 1)] = s.z;
        if (d.w >= lo && d.w < hi) csr[atomicAdd(&lcur[d.w - lo], 1)] = s.w;
    }
    int rem0 = e0 + ((e1 - e0) & ~3);
    for (int e = rem0 + tid; e < e1; e += 512) {
        int d = dst[e];
        if (d >= lo && d < hi) csr[atomicAdd(&lcur[d - lo], 1)] = src[e];
    }
}

// ---------------- gemm2 (standalone, 256 thr / 64 rows — proven R8 shape) --------
__global__ __launch_bounds__(256) void gemm2_k(
    const __half* __restrict__ A, const __half* __restrict__ WT,
    const float* __restrict__ dinv, __half* __restrict__ H, int M)
{
    __shared__ __half wlds[128][136];
    const int tid = threadIdx.x;
    {
        int r = tid >> 1, c0 = (tid & 1) * 64;
        const half8* s = (const half8*)(WT + (size_t)r * NF + c0);
        half8* d = (half8*)&wlds[r][c0];
        #pragma unroll
        for (int j = 0; j < 8; j++) d[j] = s[j];
    }
    __syncthreads();

    const int wave = tid >> 6, lane = tid & 63;
    const int quad = lane >> 4, l15 = lane & 15;
    const int rowA = blockIdx.x * 64 + wave * 16 + l15;
    const int rowc = (rowA < M) ? rowA : (M - 1);

    half8 afr[4];
    #pragma unroll
    for (int kc = 0; kc < 4; kc++)
        afr[kc] = *(const half8*)(A + (size_t)rowc * NF + kc * 32 + quad * 8);

    floatx4 acc[8];
    #pragma unroll
    for (int ct = 0; ct < 8; ct++) { floatx4 z = {0.f, 0.f, 0.f, 0.f}; acc[ct] = z; }

    #pragma unroll
    for (int kc = 0; kc < 4; kc++) {
        #pragma unroll
        for (int ct = 0; ct < 8; ct++) {
            half8 b = *(const half8*)&wlds[ct * 16 + l15][kc * 32 + quad * 8];
            acc[ct] = __builtin_amdgcn_mfma_f32_16x16x32_f16(afr[kc], b, acc[ct], 0, 0, 0);
        }
    }

    const int orow0 = blockIdx.x * 64 + wave * 16 + quad * 4;
    #pragma unroll
    for (int r = 0; r < 4; r++) {
        int orow = orow0 + r;
        if (orow < M) {
            float s = dinv[orow];
            #pragma unroll
            for (int ct = 0; ct < 8; ct++)
                H[(size_t)orow * NF + ct * 16 + l15] = __float2half(acc[ct][r] * s);
        }
    }
}

// ---------------- gather: wave/node, 2 rows/instr, 16 edges/iter (8 deep) --------
// R13 champion loop: at mean degree 16, a 16-edge group has ZERO clamped-dup
// waste (the R14/R15 32-edge form wasted ~half its loads at m=16). 0-LDS
// (R14 lesson). csr index load issued first (independent of self-row load).
__device__ __forceinline__ floatx4 gather_acc(
    const half4v* __restrict__ hs4, const int* __restrict__ csr,
    int base, int cnt, int node, int eg, int fl, int lane)
{
    floatx4 acc = {0.f, 0.f, 0.f, 0.f};
    int m0 = min(64, cnt);
    int idx0 = 0;
    if (lane < m0) idx0 = __builtin_nontemporal_load(&csr[base + lane]);  // first
    if (eg == 0) {   // self-loop
        half4v s = hs4[(size_t)node * 32 + fl];
        acc[0] = (float)s[0]; acc[1] = (float)s[1];
        acc[2] = (float)s[2]; acc[3] = (float)s[3];
    }
    for (int off = 0; off < cnt; off += 64) {
        int m = min(64, cnt - off);
        int idx = (off == 0) ? idx0 : 0;
        if (off && lane < m) idx = __builtin_nontemporal_load(&csr[base + off + lane]);
        for (int j = 0; j < m; j += 16) {   // 16 edges/iter, 8 loads in flight
            int s[8];
            half4v v[8];
            #pragma unroll
            for (int t = 0; t < 8; t++)
                s[t] = __shfl(idx, min(j + 2 * t + eg, m - 1), 64);
            #pragma unroll
            for (int t = 0; t < 8; t++)
                v[t] = hs4[(size_t)s[t] * 32 + fl];
            #pragma unroll
            for (int t = 0; t < 8; t++) {
                if (j + 2 * t + eg < m) {
                    acc[0] += (float)v[t][0]; acc[1] += (float)v[t][1];
                    acc[2] += (float)v[t][2]; acc[3] += (float)v[t][3];
                }
            }
        }
    }
    #pragma unroll
    for (int k = 0; k < 4; k++) acc[k] += __shfl_xor(acc[k], 32, 64);
    return acc;
}

// ---------------- agg: wave/node; outh fp16+relu (layer 1) or outf fp32 ----------
__global__ __launch_bounds__(256) void agg_k(
    const __half* __restrict__ hs, const int* __restrict__ rowptr,
    const int* __restrict__ csr, const float* __restrict__ dinv,
    const float* __restrict__ bias, __half* __restrict__ outh,
    float* __restrict__ outf, int n)
{
    int wave = threadIdx.x >> 6;
    int lane = threadIdx.x & 63;
    int node = blockIdx.x * 4 + wave;
    if (node >= n) return;
    const int eg = lane >> 5, fl = lane & 31;

    int base = rowptr[node];
    int cnt  = rowptr[node + 1] - base;
    floatx4 acc = gather_acc((const half4v*)hs, csr, base, cnt, node, eg, fl, lane);

    if (eg == 0) {
        float dv = dinv[node];
        float o0 = dv * acc[0] + bias[fl * 4 + 0];
        float o1 = dv * acc[1] + bias[fl * 4 + 1];
        float o2 = dv * acc[2] + bias[fl * 4 + 2];
        float o3 = dv * acc[3] + bias[fl * 4 + 3];
        if (outh) {
            half4v h;
            h[0] = (_Float16)fmaxf(o0, 0.f); h[1] = (_Float16)fmaxf(o1, 0.f);
            h[2] = (_Float16)fmaxf(o2, 0.f); h[3] = (_Float16)fmaxf(o3, 0.f);
            *(half4v*)&outh[(size_t)node * NF + fl * 4] = h;
        } else {
            floatx4 w = {o0, o1, o2, o3};
            *(floatx4*)(outf + (size_t)node * NF + fl * 4) = w;
        }
    }
}

// ---------------- launch ----------------

extern "C" void kernel_launch(void* const* d_in, const int* in_sizes, int n_in,
                              void* d_out, int out_size, void* d_ws, size_t ws_size,
                              hipStream_t stream) {
    const float* x  = (const float*)d_in[0];
    const int*   ei = (const int*)d_in[1];
    const float* W1 = (const float*)d_in[2];
    const float* b1 = (const float*)d_in[3];
    const float* W2 = (const float*)d_in[4];
    const float* b2 = (const float*)d_in[5];
    float* out = (float*)d_out;

    const int N = in_sizes[0] / NF;   // 50000
    const int E = in_sizes[1] / 2;    // 800000
    const int* src = ei;
    const int* dst = ei + E;

    char* ws = (char*)d_ws;
    size_t off = 0;
    auto alloc = [&](size_t bytes) {
        void* p = ws + off;
        off += bytes;
        off = (off + 63) & ~(size_t)63;
        return p;
    };
    unsigned char* pcnt = (unsigned char*)alloc((size_t)KC * N);  // counts->coff
    int*    rowptr  = (int*)alloc((size_t)(N + 1) * 4);   // local prefixes
    int*    rowptr2 = (int*)alloc((size_t)(N + 1) * 4);   // corrected (agg uses)
    int*    csr     = (int*)alloc((size_t)E * 4);
    float*  dinv    = (float*)alloc((size_t)N * 4);
    int*    bsum    = (int*)alloc((size_t)256 * 4);
    __half* WT1     = (__half*)alloc((size_t)NF * NF * 2);
    __half* WT2     = (__half*)alloc((size_t)NF * NF * 2);
    __half* H16     = (__half*)alloc((size_t)N * NF * 2);
    __half* A16     = (__half*)alloc((size_t)N * NF * 2);

    int nb  = (N + 255) / 256;                 // 196 (<=256)
    int Ec  = (((E + KC - 1) / KC) + 3) & ~3;  // chunk size, multiple of 4
    int GB2 = (N + 127) / 128;                 // gemm1 blocks (512 thr)
    int gb  = (N + 63) / 64;
    int ab  = (N + 3) / 4;

    count2_k<<<KC * NPART, 512, 0, stream>>>(dst, pcnt, E, N, Ec);
    pscan2_k<<<nb + 128, 256, 0, stream>>>(pcnt, dinv, rowptr, bsum, N, N, nb,
                                           W1, W2, WT1, WT2);
    mid_k<<<GB2 + KC * NPART, 512, 0, stream>>>(src, dst, rowptr, pcnt, bsum,
                                                rowptr2, csr, E, N, Ec, nb,
                                                x, WT1, dinv, H16, GB2);
    agg_k<<<ab, 256, 0, stream>>>(H16, rowptr2, csr, dinv, b1, A16, nullptr, N);
    gemm2_k<<<gb, 256, 0, stream>>>(A16, WT2, dinv, H16, N);
    agg_k<<<ab, 256, 0, stream>>>(H16, rowptr2, csr, dinv, b2, nullptr, out, N);
}